// Round 1
// baseline (833.802 us; speedup 1.0000x reference)
//
#include <hip/hip_runtime.h>
#include <stdint.h>

#define BATCH 2
#define SEQ   2048
#define DEMB  1024
#define NHEAD 16
#define DK    64
#define NTOK  (BATCH * SEQ)               // 4096
#define OUT_ELEMS ((size_t)NTOK * DEMB)   // 4194304

typedef __bf16 bf16x8 __attribute__((ext_vector_type(8)));
typedef float  f32x4  __attribute__((ext_vector_type(4)));
union FragU { uint4 u; bf16x8 b; };

__device__ __forceinline__ unsigned short f2bf(float f) {
  union { float f; unsigned u; } v; v.f = f;
  unsigned r = v.u + 0x7fffu + ((v.u >> 16) & 1u);   // RNE
  return (unsigned short)(r >> 16);
}

// async global->LDS, 16B per lane. LDS dest must be wave-uniform base + lane*16.
__device__ __forceinline__ void gll16(const void* g, void* l) {
  __builtin_amdgcn_global_load_lds(
      (const __attribute__((address_space(1))) void*)g,
      (__attribute__((address_space(3))) void*)l, 16, 0, 0);
}

// ---------------------------------------------------------------------------
// k_cvt: fp32 -> bf16 for the 3 activations and 4 weight matrices (once).
// ---------------------------------------------------------------------------
__global__ __launch_bounds__(256) void k_cvt(
    const float* __restrict__ q, const float* __restrict__ k, const float* __restrict__ v,
    const float* __restrict__ wq, const float* __restrict__ wk,
    const float* __restrict__ wv, const float* __restrict__ wo,
    unsigned short* __restrict__ dq, unsigned short* __restrict__ dk,
    unsigned short* __restrict__ dv, unsigned short* __restrict__ dwq,
    unsigned short* __restrict__ dwk, unsigned short* __restrict__ dwv,
    unsigned short* __restrict__ dwo)
{
  const int t = blockIdx.y;
  const float* s; unsigned short* d; int n4;
  switch (t) {
    case 0: s = q;  d = dq;  n4 = NTOK * DEMB / 4; break;
    case 1: s = k;  d = dk;  n4 = NTOK * DEMB / 4; break;
    case 2: s = v;  d = dv;  n4 = NTOK * DEMB / 4; break;
    case 3: s = wq; d = dwq; n4 = DEMB * DEMB / 4; break;
    case 4: s = wk; d = dwk; n4 = DEMB * DEMB / 4; break;
    case 5: s = wv; d = dwv; n4 = DEMB * DEMB / 4; break;
    default: s = wo; d = dwo; n4 = DEMB * DEMB / 4; break;
  }
  for (int i = blockIdx.x * 256 + threadIdx.x; i < n4; i += gridDim.x * 256) {
    float4 f = ((const float4*)s)[i];
    ushort4 o; o.x = f2bf(f.x); o.y = f2bf(f.y); o.z = f2bf(f.z); o.w = f2bf(f.w);
    ((ushort4*)d)[i] = o;
  }
}

// ---------------------------------------------------------------------------
// k_proj: Y^T tile GEMM: D[m=o][n=token] = sum_k W[o][k] * X[token][k] + b[o]
// Operand swap puts 4 consecutive out-features in each lane -> ushort4 stores.
// global_load_lds staging, unpadded LDS (m97 structure).
// Outputs token-major head layouts qh/kh/vh [B,H,S,64] bf16.
// ---------------------------------------------------------------------------
__global__ __launch_bounds__(256) void k_proj(
    const unsigned short* __restrict__ Xqb, const unsigned short* __restrict__ Xkb,
    const unsigned short* __restrict__ Xvb,
    const unsigned short* __restrict__ Wqb, const unsigned short* __restrict__ Wkb,
    const unsigned short* __restrict__ Wvb,
    const float* __restrict__ bq, const float* __restrict__ bk, const float* __restrict__ bv,
    unsigned short* __restrict__ qh, unsigned short* __restrict__ kh,
    unsigned short* __restrict__ vh)
{
  const int p = blockIdx.z;
  const unsigned short* __restrict__ X = (p == 0) ? Xqb : (p == 1) ? Xkb : Xvb;
  const unsigned short* __restrict__ W = (p == 0) ? Wqb : (p == 1) ? Wkb : Wvb;
  const float* __restrict__ bias       = (p == 0) ? bq  : (p == 1) ? bk  : bv;
  unsigned short* __restrict__ dst     = (p == 0) ? qh  : (p == 1) ? kh  : vh;

  __shared__ unsigned short As[128][64];   // W rows (m = o)
  __shared__ unsigned short Bs[128][64];   // X rows (n = token)

  const int tid  = threadIdx.x;
  const int lane = tid & 63;
  const int w    = tid >> 6;
  const int wm   = (w & 1) * 64;
  const int wn   = (w >> 1) * 64;
  const int l15  = lane & 15;
  const int quad = lane >> 4;

  const int o0  = blockIdx.x * 128;
  const int t0b = blockIdx.y * 128;

  f32x4 acc[4][4];
#pragma unroll
  for (int mi = 0; mi < 4; ++mi)
#pragma unroll
    for (int ni = 0; ni < 4; ++ni) acc[mi][ni] = {0.f, 0.f, 0.f, 0.f};

  for (int kk = 0; kk < DEMB; kk += 64) {
#pragma unroll
    for (int r = 0; r < 4; ++r) {
      int idx = tid + r * 256;
      int row = idx >> 3, c = (idx & 7) * 8;
      gll16(&W[(size_t)(o0 + row) * DEMB + kk + c], (unsigned short*)As + idx * 8);
      gll16(&X[(size_t)(t0b + row) * DEMB + kk + c], (unsigned short*)Bs + idx * 8);
    }
    __syncthreads();
#pragma unroll
    for (int k0 = 0; k0 < 64; k0 += 32) {
      FragU af[4], bfr[4];
#pragma unroll
      for (int mi = 0; mi < 4; ++mi)
        af[mi].u = *(const uint4*)&As[wm + mi * 16 + l15][k0 + quad * 8];
#pragma unroll
      for (int ni = 0; ni < 4; ++ni)
        bfr[ni].u = *(const uint4*)&Bs[wn + ni * 16 + l15][k0 + quad * 8];
#pragma unroll
      for (int mi = 0; mi < 4; ++mi)
#pragma unroll
        for (int ni = 0; ni < 4; ++ni)
          acc[mi][ni] = __builtin_amdgcn_mfma_f32_16x16x32_bf16(af[mi].b, bfr[ni].b, acc[mi][ni], 0, 0, 0);
    }
    __syncthreads();
  }

  // D rows: o = o0+wm+mi*16+quad*4+i (i consecutive); cols: token = t0b+wn+ni*16+l15
#pragma unroll
  for (int mi = 0; mi < 4; ++mi) {
    const int ob = o0 + wm + mi * 16 + quad * 4;
    const float4 bi = *(const float4*)&bias[ob];
    const int h_ = ob >> 6, db = ob & 63;
#pragma unroll
    for (int ni = 0; ni < 4; ++ni) {
      int token = t0b + wn + ni * 16 + l15;
      int b_ = token >> 11, s_ = token & 2047;
      ushort4 ov;
      ov.x = f2bf(acc[mi][ni][0] + bi.x);
      ov.y = f2bf(acc[mi][ni][1] + bi.y);
      ov.z = f2bf(acc[mi][ni][2] + bi.z);
      ov.w = f2bf(acc[mi][ni][3] + bi.w);
      *(ushort4*)&dst[(((size_t)b_ * NHEAD + h_) * SEQ + s_) * DK + db] = ov;
    }
  }
}

// ---------------------------------------------------------------------------
// k_vt: coalesced LDS transpose vh [bh][s][d] -> vt [bh][d][s] (once per head)
// ---------------------------------------------------------------------------
__global__ __launch_bounds__(256) void k_vt(const unsigned short* __restrict__ vh,
                                            unsigned short* __restrict__ vt)
{
  const int bh = blockIdx.y, s0 = blockIdx.x * 64;
  const size_t hoff = (size_t)bh * SEQ * DK;
  __shared__ unsigned short Ls[64][72];
  const int tid = threadIdx.x;
#pragma unroll
  for (int r = 0; r < 2; ++r) {
    int idx = tid + r * 256, row = idx >> 3, c = (idx & 7) * 8;
    uint4 v = *(const uint4*)&vh[hoff + (size_t)(s0 + row) * DK + c];
    *(uint4*)&Ls[row][c] = v;
  }
  __syncthreads();
#pragma unroll
  for (int r = 0; r < 2; ++r) {
    int idx = tid + r * 256, d = idx >> 3, c = (idx & 7) * 8;
    unsigned short tmp[8];
#pragma unroll
    for (int j = 0; j < 8; ++j) tmp[j] = Ls[c + j][d];
    *(uint4*)&vt[hoff + (size_t)d * SEQ + s0 + c] = *(const uint4*)tmp;
  }
}

// ---------------------------------------------------------------------------
// k_attn: per (head, 64 q-rows). KEY STRUCTURAL FACT: with DK=64, the K, V and
// Q tiles have ZERO intra-block reuse (each element lands in exactly one lane's
// fragment, once). So no LDS staging for them: fragments load straight from
// global (L2-resident: 256KB/head, reused across the 32 q-blocks of the head).
// Pass 1 (denominators) is barrier-free streaming MFMA. Pass 2 keeps only P in
// LDS (genuinely cross-wave shared for PV), double-buffered + 16B-chunk XOR
// swizzled (aligned reads, all 32 banks busy), one __syncthreads per K-tile.
// ---------------------------------------------------------------------------
__global__ __launch_bounds__(256, 4) void k_attn(
    const unsigned short* __restrict__ qh, const unsigned short* __restrict__ kh,
    const unsigned short* __restrict__ vt, unsigned short* __restrict__ blended,
    float* __restrict__ Pout)
{
  const int bh = blockIdx.y;
  const int s0 = blockIdx.x * 64;
  const size_t hoff = (size_t)bh * SEQ * DK;

  __shared__ unsigned short Ps[2][64][64];  // [buf][s][t], 16B-chunk swizzled
  __shared__ float rowpart[4][64];
  __shared__ float recipS[64];

  const int tid  = threadIdx.x;
  const int lane = tid & 63;
  const int w    = tid >> 6;
  const int l15  = lane & 15;
  const int quad = lane >> 4;

  // Q fragments direct from global: 8 x 16B per thread, once per block.
  FragU qf[4][2];
#pragma unroll
  for (int mi = 0; mi < 4; ++mi)
#pragma unroll
    for (int k0 = 0; k0 < 2; ++k0)
      qf[mi][k0].u = *(const uint4*)&qh[hoff + (size_t)(s0 + mi * 16 + l15) * DK + k0 * 32 + quad * 8];

  // lane-private global bases for K (A-operand rows t) and V (rows d)
  const unsigned short* kbase = kh + hoff + (size_t)(w * 16 + l15) * DK + quad * 8;
  const unsigned short* vbase = vt + hoff + (size_t)(w * 16 + l15) * SEQ + quad * 8;

  // ---- PASS 1: exp row sums. No LDS, no barriers -> loads pipeline freely.
  float rs[4] = {0.f, 0.f, 0.f, 0.f};
#pragma unroll 2
  for (int t0 = 0; t0 < SEQ; t0 += 64) {
    FragU kf0, kf1;
    kf0.u = *(const uint4*)(kbase + (size_t)t0 * DK);
    kf1.u = *(const uint4*)(kbase + (size_t)t0 * DK + 32);
#pragma unroll
    for (int mi = 0; mi < 4; ++mi) {
      f32x4 a = {0.f, 0.f, 0.f, 0.f};
      a = __builtin_amdgcn_mfma_f32_16x16x32_bf16(kf0.b, qf[mi][0].b, a, 0, 0, 0);
      a = __builtin_amdgcn_mfma_f32_16x16x32_bf16(kf1.b, qf[mi][1].b, a, 0, 0, 0);
      rs[mi] += __expf(a[0] * 0.125f) + __expf(a[1] * 0.125f)
              + __expf(a[2] * 0.125f) + __expf(a[3] * 0.125f);
    }
  }
  // reduce across quads (same s lives in lanes l15, l15+16, l15+32, l15+48)
#pragma unroll
  for (int mi = 0; mi < 4; ++mi) {
    float v = rs[mi];
    v += __shfl_xor(v, 16); v += __shfl_xor(v, 32);
    rs[mi] = v;
  }
  if (lane < 16) {
#pragma unroll
    for (int mi = 0; mi < 4; ++mi) rowpart[w][mi * 16 + lane] = rs[mi];
  }
  __syncthreads();
  if (tid < 64)
    recipS[tid] = 1.0f / (rowpart[0][tid] + rowpart[1][tid] + rowpart[2][tid] + rowpart[3][tid]);
  __syncthreads();
  float rcp[4];
#pragma unroll
  for (int mi = 0; mi < 4; ++mi) rcp[mi] = recipS[mi * 16 + l15];

  // ---- PASS 2: recompute, vectorized P write, fused PV. 1 barrier/iter.
  f32x4 accpv[4];
#pragma unroll
  for (int mi = 0; mi < 4; ++mi) accpv[mi] = {0.f, 0.f, 0.f, 0.f};

  for (int t0 = 0, buf = 0; t0 < SEQ; t0 += 64, buf ^= 1) {
    FragU kf0, kf1, vf0, vf1;
    kf0.u = *(const uint4*)(kbase + (size_t)t0 * DK);
    kf1.u = *(const uint4*)(kbase + (size_t)t0 * DK + 32);
    vf0.u = *(const uint4*)(vbase + t0);
    vf1.u = *(const uint4*)(vbase + t0 + 32);
    unsigned short* Pb = &Ps[buf][0][0];
#pragma unroll
    for (int mi = 0; mi < 4; ++mi) {
      f32x4 a = {0.f, 0.f, 0.f, 0.f};
      a = __builtin_amdgcn_mfma_f32_16x16x32_bf16(kf0.b, qf[mi][0].b, a, 0, 0, 0);
      a = __builtin_amdgcn_mfma_f32_16x16x32_bf16(kf1.b, qf[mi][1].b, a, 0, 0, 0);
      // D: rows = t-local (w*16+quad*4+i, i consecutive), cols = s-local (mi*16+l15)
      float e0 = __expf(a[0] * 0.125f) * rcp[mi];
      float e1 = __expf(a[1] * 0.125f) * rcp[mi];
      float e2 = __expf(a[2] * 0.125f) * rcp[mi];
      float e3 = __expf(a[3] * 0.125f) * rcp[mi];
      float4 p4; p4.x = e0; p4.y = e1; p4.z = e2; p4.w = e3;
      *(float4*)&Pout[((size_t)bh * SEQ + s0 + mi * 16 + l15) * SEQ + t0 + w * 16 + quad * 4] = p4;
      ushort4 pb; pb.x = f2bf(e0); pb.y = f2bf(e1); pb.z = f2bf(e2); pb.w = f2bf(e3);
      const int row = mi * 16 + l15;
      const int u   = w * 4 + quad;            // 8B unit within the row
      *(ushort4*)(Pb + row * 64 + ((((u >> 1) ^ (row & 7)) << 3) | ((u & 1) << 2))) = pb;
    }
    __syncthreads();
    // PV with A=V (m=d), B=P (n=s): accpv rows = d (quad*4+i consecutive)
#pragma unroll
    for (int mi = 0; mi < 4; ++mi) {
      const int row = mi * 16 + l15;
      FragU pf0, pf1;
      pf0.u = *(const uint4*)(Pb + row * 64 + ((quad ^ (row & 7)) << 3));
      pf1.u = *(const uint4*)(Pb + row * 64 + (((4 + quad) ^ (row & 7)) << 3));
      accpv[mi] = __builtin_amdgcn_mfma_f32_16x16x32_bf16(vf0.b, pf0.b, accpv[mi], 0, 0, 0);
      accpv[mi] = __builtin_amdgcn_mfma_f32_16x16x32_bf16(vf1.b, pf1.b, accpv[mi], 0, 0, 0);
    }
  }

  // blended: d = w*16+quad*4+i (packed), s = mi*16+l15
  const int b_ = bh >> 4, h_ = bh & 15;
#pragma unroll
  for (int mi = 0; mi < 4; ++mi) {
    ushort4 ob;
    ob.x = f2bf(accpv[mi][0]); ob.y = f2bf(accpv[mi][1]);
    ob.z = f2bf(accpv[mi][2]); ob.w = f2bf(accpv[mi][3]);
    int token = b_ * SEQ + s0 + mi * 16 + l15;
    *(ushort4*)&blended[(size_t)token * DEMB + h_ * DK + w * 16 + quad * 4] = ob;
  }
}

// ---------------------------------------------------------------------------
// k_outproj: D[m=o][n=token] = sum_k Wo[o][k] * blended[token][k] + bo[o]
// float4 stores (4 consecutive o per lane).
// ---------------------------------------------------------------------------
__global__ __launch_bounds__(256) void k_outproj(
    const unsigned short* __restrict__ Wob, const unsigned short* __restrict__ blended,
    const float* __restrict__ bo, float* __restrict__ out)
{
  __shared__ unsigned short As[128][64];   // Wo rows (m = o)
  __shared__ unsigned short Bs[128][64];   // blended rows (n = token)

  const int tid  = threadIdx.x;
  const int lane = tid & 63;
  const int w    = tid >> 6;
  const int wm   = (w & 1) * 64;
  const int wn   = (w >> 1) * 64;
  const int l15  = lane & 15;
  const int quad = lane >> 4;

  const int o0  = blockIdx.x * 128;
  const int t0b = blockIdx.y * 128;

  f32x4 acc[4][4];
#pragma unroll
  for (int mi = 0; mi < 4; ++mi)
#pragma unroll
    for (int ni = 0; ni < 4; ++ni) acc[mi][ni] = {0.f, 0.f, 0.f, 0.f};

  for (int kk = 0; kk < DEMB; kk += 64) {
#pragma unroll
    for (int r = 0; r < 4; ++r) {
      int idx = tid + r * 256;
      int row = idx >> 3, c = (idx & 7) * 8;
      gll16(&Wob[(size_t)(o0 + row) * DEMB + kk + c], (unsigned short*)As + idx * 8);
      gll16(&blended[(size_t)(t0b + row) * DEMB + kk + c], (unsigned short*)Bs + idx * 8);
    }
    __syncthreads();
#pragma unroll
    for (int k0 = 0; k0 < 64; k0 += 32) {
      FragU af[4], bfr[4];
#pragma unroll
      for (int mi = 0; mi < 4; ++mi)
        af[mi].u = *(const uint4*)&As[wm + mi * 16 + l15][k0 + quad * 8];
#pragma unroll
      for (int ni = 0; ni < 4; ++ni)
        bfr[ni].u = *(const uint4*)&Bs[wn + ni * 16 + l15][k0 + quad * 8];
#pragma unroll
      for (int mi = 0; mi < 4; ++mi)
#pragma unroll
        for (int ni = 0; ni < 4; ++ni)
          acc[mi][ni] = __builtin_amdgcn_mfma_f32_16x16x32_bf16(af[mi].b, bfr[ni].b, acc[mi][ni], 0, 0, 0);
    }
    __syncthreads();
  }

#pragma unroll
  for (int mi = 0; mi < 4; ++mi) {
    const int ob = o0 + wm + mi * 16 + quad * 4;
    const float4 bi = *(const float4*)&bo[ob];
#pragma unroll
    for (int ni = 0; ni < 4; ++ni) {
      int token = t0b + wn + ni * 16 + l15;
      float4 ov;
      ov.x = acc[mi][ni][0] + bi.x;
      ov.y = acc[mi][ni][1] + bi.y;
      ov.z = acc[mi][ni][2] + bi.z;
      ov.w = acc[mi][ni][3] + bi.w;
      *(float4*)&out[(size_t)token * DEMB + ob] = ov;
    }
  }
}

// ---------------------------------------------------------------------------
extern "C" void kernel_launch(void* const* d_in, const int* in_sizes, int n_in,
                              void* d_out, int out_size, void* d_ws, size_t ws_size,
                              hipStream_t stream) {
  const float* Xq = (const float*)d_in[0];
  const float* Xk = (const float*)d_in[1];
  const float* Xv = (const float*)d_in[2];
  const float* Wq = (const float*)d_in[3];
  const float* bq = (const float*)d_in[4];
  const float* Wk = (const float*)d_in[5];
  const float* bk = (const float*)d_in[6];
  const float* Wv = (const float*)d_in[7];
  const float* bv = (const float*)d_in[8];
  const float* Wo = (const float*)d_in[9];
  const float* bo = (const float*)d_in[10];

  float* out  = (float*)d_out;
  float* Pout = out + OUT_ELEMS;

  // ws layout (bf16): 3 activations, 4 weights, qh/kh/vh/vt/blended
  unsigned short* Xqb = (unsigned short*)d_ws;
  unsigned short* Xkb = Xqb + OUT_ELEMS;
  unsigned short* Xvb = Xkb + OUT_ELEMS;
  unsigned short* Wqb = Xvb + OUT_ELEMS;
  unsigned short* Wkb = Wqb + (size_t)DEMB * DEMB;
  unsigned short* Wvb = Wkb + (size_t)DEMB * DEMB;
  unsigned short* Wob = Wvb + (size_t)DEMB * DEMB;
  unsigned short* qh      = Wob + (size_t)DEMB * DEMB;
  unsigned short* kh      = qh + OUT_ELEMS;
  unsigned short* vh      = kh + OUT_ELEMS;
  unsigned short* vt      = vh + OUT_ELEMS;
  unsigned short* blended = vt + OUT_ELEMS;

  k_cvt<<<dim3(1024, 7), 256, 0, stream>>>(Xq, Xk, Xv, Wq, Wk, Wv, Wo,
                                           Xqb, Xkb, Xvb, Wqb, Wkb, Wvb, Wob);
  k_proj<<<dim3(8, 32, 3), 256, 0, stream>>>(Xqb, Xkb, Xvb, Wqb, Wkb, Wvb,
                                             bq, bk, bv, qh, kh, vh);
  k_vt<<<dim3(32, 32), 256, 0, stream>>>(vh, vt);
  k_attn<<<dim3(SEQ / 64, BATCH * NHEAD), 256, 0, stream>>>(qh, kh, vt, blended, Pout);
  k_outproj<<<dim3(8, 32), 256, 0, stream>>>(Wob, blended, bo, out);
}

// Round 2
// 814.644 us; speedup vs baseline: 1.0235x; 1.0235x over previous
//
#include <hip/hip_runtime.h>
#include <stdint.h>

#define BATCH 2
#define SEQ   2048
#define DEMB  1024
#define NHEAD 16
#define DK    64
#define NTOK  (BATCH * SEQ)               // 4096
#define OUT_ELEMS ((size_t)NTOK * DEMB)   // 4194304

typedef __bf16 bf16x8 __attribute__((ext_vector_type(8)));
typedef float  f32x4  __attribute__((ext_vector_type(4)));
union FragU { uint4 u; bf16x8 b; };

__device__ __forceinline__ unsigned short f2bf(float f) {
  union { float f; unsigned u; } v; v.f = f;
  unsigned r = v.u + 0x7fffu + ((v.u >> 16) & 1u);   // RNE
  return (unsigned short)(r >> 16);
}

// async global->LDS, 16B per lane. LDS dest must be wave-uniform base + lane*16.
__device__ __forceinline__ void gll16(const void* g, void* l) {
  __builtin_amdgcn_global_load_lds(
      (const __attribute__((address_space(1))) void*)g,
      (__attribute__((address_space(3))) void*)l, 16, 0, 0);
}

// raw barriers with hand-counted waits (avoid __syncthreads' full vmcnt drain)
#define BAR_VM0()  asm volatile("s_waitcnt vmcnt(0) lgkmcnt(0)\n\ts_barrier" ::: "memory")
#define BAR_LGKM() asm volatile("s_waitcnt lgkmcnt(0)\n\ts_barrier" ::: "memory")
#define BAR_VM4()  asm volatile("s_waitcnt vmcnt(4) lgkmcnt(0)\n\ts_barrier" ::: "memory")

// ---------------------------------------------------------------------------
// k_cvt: fp32 -> bf16 for the 3 activations and 4 weight matrices (once).
// ---------------------------------------------------------------------------
__global__ __launch_bounds__(256) void k_cvt(
    const float* __restrict__ q, const float* __restrict__ k, const float* __restrict__ v,
    const float* __restrict__ wq, const float* __restrict__ wk,
    const float* __restrict__ wv, const float* __restrict__ wo,
    unsigned short* __restrict__ dq, unsigned short* __restrict__ dk,
    unsigned short* __restrict__ dv, unsigned short* __restrict__ dwq,
    unsigned short* __restrict__ dwk, unsigned short* __restrict__ dwv,
    unsigned short* __restrict__ dwo)
{
  const int t = blockIdx.y;
  const float* s; unsigned short* d; int n4;
  switch (t) {
    case 0: s = q;  d = dq;  n4 = NTOK * DEMB / 4; break;
    case 1: s = k;  d = dk;  n4 = NTOK * DEMB / 4; break;
    case 2: s = v;  d = dv;  n4 = NTOK * DEMB / 4; break;
    case 3: s = wq; d = dwq; n4 = DEMB * DEMB / 4; break;
    case 4: s = wk; d = dwk; n4 = DEMB * DEMB / 4; break;
    case 5: s = wv; d = dwv; n4 = DEMB * DEMB / 4; break;
    default: s = wo; d = dwo; n4 = DEMB * DEMB / 4; break;
  }
  for (int i = blockIdx.x * 256 + threadIdx.x; i < n4; i += gridDim.x * 256) {
    float4 f = ((const float4*)s)[i];
    ushort4 o; o.x = f2bf(f.x); o.y = f2bf(f.y); o.z = f2bf(f.z); o.w = f2bf(f.w);
    ((ushort4*)d)[i] = o;
  }
}

// ---------------------------------------------------------------------------
// k_proj: Y^T tile GEMM: D[m=o][n=token] = sum_k W[o][k] * X[token][k] + b[o]
// ---------------------------------------------------------------------------
__global__ __launch_bounds__(256) void k_proj(
    const unsigned short* __restrict__ Xqb, const unsigned short* __restrict__ Xkb,
    const unsigned short* __restrict__ Xvb,
    const unsigned short* __restrict__ Wqb, const unsigned short* __restrict__ Wkb,
    const unsigned short* __restrict__ Wvb,
    const float* __restrict__ bq, const float* __restrict__ bk, const float* __restrict__ bv,
    unsigned short* __restrict__ qh, unsigned short* __restrict__ kh,
    unsigned short* __restrict__ vh)
{
  const int p = blockIdx.z;
  const unsigned short* __restrict__ X = (p == 0) ? Xqb : (p == 1) ? Xkb : Xvb;
  const unsigned short* __restrict__ W = (p == 0) ? Wqb : (p == 1) ? Wkb : Wvb;
  const float* __restrict__ bias       = (p == 0) ? bq  : (p == 1) ? bk  : bv;
  unsigned short* __restrict__ dst     = (p == 0) ? qh  : (p == 1) ? kh  : vh;

  __shared__ unsigned short As[128][64];   // W rows (m = o)
  __shared__ unsigned short Bs[128][64];   // X rows (n = token)

  const int tid  = threadIdx.x;
  const int lane = tid & 63;
  const int w    = tid >> 6;
  const int wm   = (w & 1) * 64;
  const int wn   = (w >> 1) * 64;
  const int l15  = lane & 15;
  const int quad = lane >> 4;

  const int o0  = blockIdx.x * 128;
  const int t0b = blockIdx.y * 128;

  f32x4 acc[4][4];
#pragma unroll
  for (int mi = 0; mi < 4; ++mi)
#pragma unroll
    for (int ni = 0; ni < 4; ++ni) acc[mi][ni] = {0.f, 0.f, 0.f, 0.f};

  for (int kk = 0; kk < DEMB; kk += 64) {
#pragma unroll
    for (int r = 0; r < 4; ++r) {
      int idx = tid + r * 256;
      int row = idx >> 3, c = (idx & 7) * 8;
      gll16(&W[(size_t)(o0 + row) * DEMB + kk + c], (unsigned short*)As + idx * 8);
      gll16(&X[(size_t)(t0b + row) * DEMB + kk + c], (unsigned short*)Bs + idx * 8);
    }
    __syncthreads();
#pragma unroll
    for (int k0 = 0; k0 < 64; k0 += 32) {
      FragU af[4], bfr[4];
#pragma unroll
      for (int mi = 0; mi < 4; ++mi)
        af[mi].u = *(const uint4*)&As[wm + mi * 16 + l15][k0 + quad * 8];
#pragma unroll
      for (int ni = 0; ni < 4; ++ni)
        bfr[ni].u = *(const uint4*)&Bs[wn + ni * 16 + l15][k0 + quad * 8];
#pragma unroll
      for (int mi = 0; mi < 4; ++mi)
#pragma unroll
        for (int ni = 0; ni < 4; ++ni)
          acc[mi][ni] = __builtin_amdgcn_mfma_f32_16x16x32_bf16(af[mi].b, bfr[ni].b, acc[mi][ni], 0, 0, 0);
    }
    __syncthreads();
  }

#pragma unroll
  for (int mi = 0; mi < 4; ++mi) {
    const int ob = o0 + wm + mi * 16 + quad * 4;
    const float4 bi = *(const float4*)&bias[ob];
    const int h_ = ob >> 6, db = ob & 63;
#pragma unroll
    for (int ni = 0; ni < 4; ++ni) {
      int token = t0b + wn + ni * 16 + l15;
      int b_ = token >> 11, s_ = token & 2047;
      ushort4 ov;
      ov.x = f2bf(acc[mi][ni][0] + bi.x);
      ov.y = f2bf(acc[mi][ni][1] + bi.y);
      ov.z = f2bf(acc[mi][ni][2] + bi.z);
      ov.w = f2bf(acc[mi][ni][3] + bi.w);
      *(ushort4*)&dst[(((size_t)b_ * NHEAD + h_) * SEQ + s_) * DK + db] = ov;
    }
  }
}

// ---------------------------------------------------------------------------
// k_vt: coalesced LDS transpose vh [bh][s][d] -> vt [bh][d][s]
// ---------------------------------------------------------------------------
__global__ __launch_bounds__(256) void k_vt(const unsigned short* __restrict__ vh,
                                            unsigned short* __restrict__ vt)
{
  const int bh = blockIdx.y, s0 = blockIdx.x * 64;
  const size_t hoff = (size_t)bh * SEQ * DK;
  __shared__ unsigned short Ls[64][72];
  const int tid = threadIdx.x;
#pragma unroll
  for (int r = 0; r < 2; ++r) {
    int idx = tid + r * 256, row = idx >> 3, c = (idx & 7) * 8;
    uint4 v = *(const uint4*)&vh[hoff + (size_t)(s0 + row) * DK + c];
    *(uint4*)&Ls[row][c] = v;
  }
  __syncthreads();
#pragma unroll
  for (int r = 0; r < 2; ++r) {
    int idx = tid + r * 256, d = idx >> 3, c = (idx & 7) * 8;
    unsigned short tmp[8];
#pragma unroll
    for (int j = 0; j < 8; ++j) tmp[j] = Ls[c + j][d];
    *(uint4*)&vt[hoff + (size_t)d * SEQ + s0 + c] = *(const uint4*)tmp;
  }
}

// ---------------------------------------------------------------------------
// k_attn: per (head, 64 q-rows). gll16 staging RESTORED (round-1's direct
// per-lane loads regressed), now double-buffered with raw barriers and
// hand-counted s_waitcnt so Pout stores and next-tile staging are never
// drained at a barrier. K/V staged with SOURCE-swizzled addresses (LDS dest
// linear, m173 pattern) -> conflict-free ds_read_b128 fragments.
//   pass 1: 1 barrier/iter (vmcnt(0): only the 1-phase-old prefetch).
//   pass 2: 2 barriers/iter: mid = lgkmcnt(0) only (publish Ps; stores +
//           staging ride across), end = vmcnt(4) (retire exactly the 4
//           staging loads; the 4 Pout stores stay in flight).
// V frags are read pre-mid-barrier -> PV needs only Ps from LDS -> single
// Ps buffer; pass-1 scratch aliases Ps -> LDS = 40KB total.
// ---------------------------------------------------------------------------
__global__ __launch_bounds__(256, 3) void k_attn(
    const unsigned short* __restrict__ qh, const unsigned short* __restrict__ kh,
    const unsigned short* __restrict__ vt, unsigned short* __restrict__ blended,
    float* __restrict__ Pout)
{
  const int bh = blockIdx.y;
  const int s0 = blockIdx.x * 64;
  const size_t hoff = (size_t)bh * SEQ * DK;

  __shared__ unsigned short Ks[2][64][64];   // 16KB, double-buffered
  __shared__ unsigned short Vs[2][64][64];   // 16KB, double-buffered ([d][t])
  __shared__ unsigned short Ps[64][64];      // 8KB, single buffer, swizzled
  float* rowpart = (float*)&Ps[0][0];        // pass-1 scratch aliased onto Ps
  float* recipS  = rowpart + 256;

  const int tid  = threadIdx.x;
  const int lane = tid & 63;
  const int w    = tid >> 6;
  const int l15  = lane & 15;
  const int quad = lane >> 4;
  const int rx   = l15 & 7;

  // staging chunk mapping: LDS[r][j] holds global chunk (j ^ (r&7)) of row r
  const int p0 = tid, p1 = tid + 256;
  const int r0 = p0 >> 3, c0 = ((p0 & 7) ^ (r0 & 7)) * 8;
  const int r1 = p1 >> 3, c1 = ((p1 & 7) ^ (r1 & 7)) * 8;

  // Q fragments direct from global: once per block, L2-resident.
  FragU qf[4][2];
#pragma unroll
  for (int mi = 0; mi < 4; ++mi)
#pragma unroll
    for (int k0 = 0; k0 < 2; ++k0)
      qf[mi][k0].u = *(const uint4*)&qh[hoff + (size_t)(s0 + mi * 16 + l15) * DK + k0 * 32 + quad * 8];

  const int rr = w * 16 + l15;          // K/V LDS row this lane's fragment uses
  const int fc0 = (quad ^ rx) * 8;      // swizzled frag chunk offsets (elems)
  const int fc1 = ((quad + 4) ^ rx) * 8;

  // ---- PASS 1: exp row sums. Double-buffered K staging, 1 barrier/iter.
  float rs[4] = {0.f, 0.f, 0.f, 0.f};
  gll16(&kh[hoff + (size_t)r0 * DK + c0], (unsigned short*)Ks[0] + p0 * 8);
  gll16(&kh[hoff + (size_t)r1 * DK + c1], (unsigned short*)Ks[0] + p1 * 8);
  BAR_VM0();
  for (int i = 0; i < 32; ++i) {
    const int b = i & 1;
    const size_t tn = (size_t)(((i + 1) & 31) * 64);   // wraparound prefetch
    gll16(&kh[hoff + (tn + r0) * DK + c0], (unsigned short*)Ks[b ^ 1] + p0 * 8);
    gll16(&kh[hoff + (tn + r1) * DK + c1], (unsigned short*)Ks[b ^ 1] + p1 * 8);
    FragU kf0, kf1;
    kf0.u = *(const uint4*)&Ks[b][rr][fc0];
    kf1.u = *(const uint4*)&Ks[b][rr][fc1];
#pragma unroll
    for (int mi = 0; mi < 4; ++mi) {
      f32x4 a = {0.f, 0.f, 0.f, 0.f};
      a = __builtin_amdgcn_mfma_f32_16x16x32_bf16(kf0.b, qf[mi][0].b, a, 0, 0, 0);
      a = __builtin_amdgcn_mfma_f32_16x16x32_bf16(kf1.b, qf[mi][1].b, a, 0, 0, 0);
      rs[mi] += __expf(a[0] * 0.125f) + __expf(a[1] * 0.125f)
              + __expf(a[2] * 0.125f) + __expf(a[3] * 0.125f);
    }
    BAR_VM0();
  }
  // reduce across quads (same s lives in lanes l15, l15+16, l15+32, l15+48)
#pragma unroll
  for (int mi = 0; mi < 4; ++mi) {
    float v = rs[mi];
    v += __shfl_xor(v, 16); v += __shfl_xor(v, 32);
    rs[mi] = v;
  }
  if (lane < 16) {
#pragma unroll
    for (int mi = 0; mi < 4; ++mi) rowpart[w * 64 + mi * 16 + lane] = rs[mi];
  }
  __syncthreads();
  if (tid < 64)
    recipS[tid] = 1.0f / (rowpart[tid] + rowpart[64 + tid] + rowpart[128 + tid] + rowpart[192 + tid]);
  __syncthreads();
  float rcp[4];
#pragma unroll
  for (int mi = 0; mi < 4; ++mi) rcp[mi] = recipS[mi * 16 + l15];

  // ---- PASS 2 ----
  f32x4 accpv[4];
#pragma unroll
  for (int mi = 0; mi < 4; ++mi) accpv[mi] = {0.f, 0.f, 0.f, 0.f};

  // prologue: stage tile 0 (K into Ks[0], V into Vs[0])
  gll16(&kh[hoff + (size_t)r0 * DK + c0], (unsigned short*)Ks[0] + p0 * 8);
  gll16(&kh[hoff + (size_t)r1 * DK + c1], (unsigned short*)Ks[0] + p1 * 8);
  gll16(&vt[hoff + (size_t)r0 * SEQ + c0], (unsigned short*)Vs[0] + p0 * 8);
  gll16(&vt[hoff + (size_t)r1 * SEQ + c1], (unsigned short*)Vs[0] + p1 * 8);
  BAR_VM0();   // lgkmcnt(0) also fences the recipS reads vs upcoming Ps writes

  const int u   = w * 4 + quad;   // 8B unit within a P row
  const int psw = (((u >> 1) ^ rx) << 3) | ((u & 1) << 2);   // P write offs (elems)
  const int pr0 = (quad ^ rx) << 3;                          // P read offs
  const int pr1 = ((quad + 4) ^ rx) << 3;

  for (int i = 0; i < 32; ++i) {
    const int b  = i & 1;
    const int t0 = i * 64;
    const size_t tn = (size_t)(((i + 1) & 31) * 64);
    // stage tile i+1 -> buffers b^1 (4 gll16, issued BEFORE the Pout stores)
    gll16(&kh[hoff + (tn + r0) * DK + c0], (unsigned short*)Ks[b ^ 1] + p0 * 8);
    gll16(&kh[hoff + (tn + r1) * DK + c1], (unsigned short*)Ks[b ^ 1] + p1 * 8);
    gll16(&vt[hoff + (size_t)r0 * SEQ + tn + c0], (unsigned short*)Vs[b ^ 1] + p0 * 8);
    gll16(&vt[hoff + (size_t)r1 * SEQ + tn + c1], (unsigned short*)Vs[b ^ 1] + p1 * 8);
    // fragments for tile i (staged >=1 barrier ago)
    FragU kf0, kf1, vf0, vf1;
    kf0.u = *(const uint4*)&Ks[b][rr][fc0];
    kf1.u = *(const uint4*)&Ks[b][rr][fc1];
    vf0.u = *(const uint4*)&Vs[b][rr][fc0];   // read pre-barrier: PV uses regs
    vf1.u = *(const uint4*)&Vs[b][rr][fc1];
#pragma unroll
    for (int mi = 0; mi < 4; ++mi) {
      f32x4 a = {0.f, 0.f, 0.f, 0.f};
      a = __builtin_amdgcn_mfma_f32_16x16x32_bf16(kf0.b, qf[mi][0].b, a, 0, 0, 0);
      a = __builtin_amdgcn_mfma_f32_16x16x32_bf16(kf1.b, qf[mi][1].b, a, 0, 0, 0);
      // D: rows = t-local (w*16+quad*4+i), cols = s-local (mi*16+l15)
      float e0 = __expf(a[0] * 0.125f) * rcp[mi];
      float e1 = __expf(a[1] * 0.125f) * rcp[mi];
      float e2 = __expf(a[2] * 0.125f) * rcp[mi];
      float e3 = __expf(a[3] * 0.125f) * rcp[mi];
      float4 p4; p4.x = e0; p4.y = e1; p4.z = e2; p4.w = e3;
      *(float4*)&Pout[((size_t)bh * SEQ + s0 + mi * 16 + l15) * SEQ + t0 + w * 16 + quad * 4] = p4;
      ushort4 pb; pb.x = f2bf(e0); pb.y = f2bf(e1); pb.z = f2bf(e2); pb.w = f2bf(e3);
      *(ushort4*)((unsigned short*)&Ps[mi * 16 + l15][0] + psw) = pb;
    }
    BAR_LGKM();   // publish Ps; Pout stores + staging stay in flight
    // PV with A=V (m=d), B=P (n=s): accpv rows = d (quad*4+i consecutive)
#pragma unroll
    for (int mi = 0; mi < 4; ++mi) {
      FragU pf0, pf1;
      pf0.u = *(const uint4*)((const unsigned short*)&Ps[mi * 16 + l15][0] + pr0);
      pf1.u = *(const uint4*)((const unsigned short*)&Ps[mi * 16 + l15][0] + pr1);
      accpv[mi] = __builtin_amdgcn_mfma_f32_16x16x32_bf16(vf0.b, pf0.b, accpv[mi], 0, 0, 0);
      accpv[mi] = __builtin_amdgcn_mfma_f32_16x16x32_bf16(vf1.b, pf1.b, accpv[mi], 0, 0, 0);
    }
    BAR_VM4();    // retire exactly the 4 staging loads; stores ride on
  }

  // blended: d = w*16+quad*4+i (packed), s = mi*16+l15
  const int b_ = bh >> 4, h_ = bh & 15;
#pragma unroll
  for (int mi = 0; mi < 4; ++mi) {
    ushort4 ob;
    ob.x = f2bf(accpv[mi][0]); ob.y = f2bf(accpv[mi][1]);
    ob.z = f2bf(accpv[mi][2]); ob.w = f2bf(accpv[mi][3]);
    int token = b_ * SEQ + s0 + mi * 16 + l15;
    *(ushort4*)&blended[(size_t)token * DEMB + h_ * DK + w * 16 + quad * 4] = ob;
  }
}

// ---------------------------------------------------------------------------
// k_outproj: D[m=o][n=token] = sum_k Wo[o][k] * blended[token][k] + bo[o]
// ---------------------------------------------------------------------------
__global__ __launch_bounds__(256) void k_outproj(
    const unsigned short* __restrict__ Wob, const unsigned short* __restrict__ blended,
    const float* __restrict__ bo, float* __restrict__ out)
{
  __shared__ unsigned short As[128][64];   // Wo rows (m = o)
  __shared__ unsigned short Bs[128][64];   // blended rows (n = token)

  const int tid  = threadIdx.x;
  const int lane = tid & 63;
  const int w    = tid >> 6;
  const int wm   = (w & 1) * 64;
  const int wn   = (w >> 1) * 64;
  const int l15  = lane & 15;
  const int quad = lane >> 4;

  const int o0  = blockIdx.x * 128;
  const int t0b = blockIdx.y * 128;

  f32x4 acc[4][4];
#pragma unroll
  for (int mi = 0; mi < 4; ++mi)
#pragma unroll
    for (int ni = 0; ni < 4; ++ni) acc[mi][ni] = {0.f, 0.f, 0.f, 0.f};

  for (int kk = 0; kk < DEMB; kk += 64) {
#pragma unroll
    for (int r = 0; r < 4; ++r) {
      int idx = tid + r * 256;
      int row = idx >> 3, c = (idx & 7) * 8;
      gll16(&Wob[(size_t)(o0 + row) * DEMB + kk + c], (unsigned short*)As + idx * 8);
      gll16(&blended[(size_t)(t0b + row) * DEMB + kk + c], (unsigned short*)Bs + idx * 8);
    }
    __syncthreads();
#pragma unroll
    for (int k0 = 0; k0 < 64; k0 += 32) {
      FragU af[4], bfr[4];
#pragma unroll
      for (int mi = 0; mi < 4; ++mi)
        af[mi].u = *(const uint4*)&As[wm + mi * 16 + l15][k0 + quad * 8];
#pragma unroll
      for (int ni = 0; ni < 4; ++ni)
        bfr[ni].u = *(const uint4*)&Bs[wn + ni * 16 + l15][k0 + quad * 8];
#pragma unroll
      for (int mi = 0; mi < 4; ++mi)
#pragma unroll
        for (int ni = 0; ni < 4; ++ni)
          acc[mi][ni] = __builtin_amdgcn_mfma_f32_16x16x32_bf16(af[mi].b, bfr[ni].b, acc[mi][ni], 0, 0, 0);
    }
    __syncthreads();
  }

#pragma unroll
  for (int mi = 0; mi < 4; ++mi) {
    const int ob = o0 + wm + mi * 16 + quad * 4;
    const float4 bi = *(const float4*)&bo[ob];
#pragma unroll
    for (int ni = 0; ni < 4; ++ni) {
      int token = t0b + wn + ni * 16 + l15;
      float4 ov;
      ov.x = acc[mi][ni][0] + bi.x;
      ov.y = acc[mi][ni][1] + bi.y;
      ov.z = acc[mi][ni][2] + bi.z;
      ov.w = acc[mi][ni][3] + bi.w;
      *(float4*)&out[(size_t)token * DEMB + ob] = ov;
    }
  }
}

// ---------------------------------------------------------------------------
extern "C" void kernel_launch(void* const* d_in, const int* in_sizes, int n_in,
                              void* d_out, int out_size, void* d_ws, size_t ws_size,
                              hipStream_t stream) {
  const float* Xq = (const float*)d_in[0];
  const float* Xk = (const float*)d_in[1];
  const float* Xv = (const float*)d_in[2];
  const float* Wq = (const float*)d_in[3];
  const float* bq = (const float*)d_in[4];
  const float* Wk = (const float*)d_in[5];
  const float* bk = (const float*)d_in[6];
  const float* Wv = (const float*)d_in[7];
  const float* bv = (const float*)d_in[8];
  const float* Wo = (const float*)d_in[9];
  const float* bo = (const float*)d_in[10];

  float* out  = (float*)d_out;
  float* Pout = out + OUT_ELEMS;

  // ws layout (bf16): 3 activations, 4 weights, qh/kh/vh/vt/blended
  unsigned short* Xqb = (unsigned short*)d_ws;
  unsigned short* Xkb = Xqb + OUT_ELEMS;
  unsigned short* Xvb = Xkb + OUT_ELEMS;
  unsigned short* Wqb = Xvb + OUT_ELEMS;
  unsigned short* Wkb = Wqb + (size_t)DEMB * DEMB;
  unsigned short* Wvb = Wkb + (size_t)DEMB * DEMB;
  unsigned short* Wob = Wvb + (size_t)DEMB * DEMB;
  unsigned short* qh      = Wob + (size_t)DEMB * DEMB;
  unsigned short* kh      = qh + OUT_ELEMS;
  unsigned short* vh      = kh + OUT_ELEMS;
  unsigned short* vt      = vh + OUT_ELEMS;
  unsigned short* blended = vt + OUT_ELEMS;

  k_cvt<<<dim3(1024, 7), 256, 0, stream>>>(Xq, Xk, Xv, Wq, Wk, Wv, Wo,
                                           Xqb, Xkb, Xvb, Wqb, Wkb, Wvb, Wob);
  k_proj<<<dim3(8, 32, 3), 256, 0, stream>>>(Xqb, Xkb, Xvb, Wqb, Wkb, Wvb,
                                             bq, bk, bv, qh, kh, vh);
  k_vt<<<dim3(32, 32), 256, 0, stream>>>(vh, vt);
  k_attn<<<dim3(SEQ / 64, BATCH * NHEAD), 256, 0, stream>>>(qh, kh, vt, blended, Pout);
  k_outproj<<<dim3(8, 32), 256, 0, stream>>>(Wob, blended, bo, out);
}

// Round 3
// 789.665 us; speedup vs baseline: 1.0559x; 1.0316x over previous
//
#include <hip/hip_runtime.h>
#include <stdint.h>

#define BATCH 2
#define SEQ   2048
#define DEMB  1024
#define NHEAD 16
#define DK    64
#define NTOK  (BATCH * SEQ)               // 4096
#define OUT_ELEMS ((size_t)NTOK * DEMB)   // 4194304

typedef __bf16 bf16x8 __attribute__((ext_vector_type(8)));
typedef float  f32x4  __attribute__((ext_vector_type(4)));
union FragU { uint4 u; bf16x8 b; };

__device__ __forceinline__ unsigned short f2bf(float f) {
  union { float f; unsigned u; } v; v.f = f;
  unsigned r = v.u + 0x7fffu + ((v.u >> 16) & 1u);   // RNE
  return (unsigned short)(r >> 16);
}

// async global->LDS, 16B per lane. LDS dest must be wave-uniform base + lane*16.
__device__ __forceinline__ void gll16(const void* g, void* l) {
  __builtin_amdgcn_global_load_lds(
      (const __attribute__((address_space(1))) void*)g,
      (__attribute__((address_space(3))) void*)l, 16, 0, 0);
}

// raw barriers with hand-counted waits (avoid __syncthreads' full vmcnt drain)
#define BAR_VM0()  asm volatile("s_waitcnt vmcnt(0) lgkmcnt(0)\n\ts_barrier" ::: "memory")
#define BAR_LGKM() asm volatile("s_waitcnt lgkmcnt(0)\n\ts_barrier" ::: "memory")
#define BAR_VM4()  asm volatile("s_waitcnt vmcnt(4) lgkmcnt(0)\n\ts_barrier" ::: "memory")

// ---------------------------------------------------------------------------
// k_cvt: fp32 -> bf16 for the 3 activations and 4 weight matrices (once).
// ---------------------------------------------------------------------------
__global__ __launch_bounds__(256) void k_cvt(
    const float* __restrict__ q, const float* __restrict__ k, const float* __restrict__ v,
    const float* __restrict__ wq, const float* __restrict__ wk,
    const float* __restrict__ wv, const float* __restrict__ wo,
    unsigned short* __restrict__ dq, unsigned short* __restrict__ dk,
    unsigned short* __restrict__ dv, unsigned short* __restrict__ dwq,
    unsigned short* __restrict__ dwk, unsigned short* __restrict__ dwv,
    unsigned short* __restrict__ dwo)
{
  const int t = blockIdx.y;
  const float* s; unsigned short* d; int n4;
  switch (t) {
    case 0: s = q;  d = dq;  n4 = NTOK * DEMB / 4; break;
    case 1: s = k;  d = dk;  n4 = NTOK * DEMB / 4; break;
    case 2: s = v;  d = dv;  n4 = NTOK * DEMB / 4; break;
    case 3: s = wq; d = dwq; n4 = DEMB * DEMB / 4; break;
    case 4: s = wk; d = dwk; n4 = DEMB * DEMB / 4; break;
    case 5: s = wv; d = dwv; n4 = DEMB * DEMB / 4; break;
    default: s = wo; d = dwo; n4 = DEMB * DEMB / 4; break;
  }
  for (int i = blockIdx.x * 256 + threadIdx.x; i < n4; i += gridDim.x * 256) {
    float4 f = ((const float4*)s)[i];
    ushort4 o; o.x = f2bf(f.x); o.y = f2bf(f.y); o.z = f2bf(f.z); o.w = f2bf(f.w);
    ((ushort4*)d)[i] = o;
  }
}

// ---------------------------------------------------------------------------
// k_proj: Y^T tile GEMM: D[m=o][n=token] = sum_k W[o][k] * X[token][k] + b[o]
// ---------------------------------------------------------------------------
__global__ __launch_bounds__(256) void k_proj(
    const unsigned short* __restrict__ Xqb, const unsigned short* __restrict__ Xkb,
    const unsigned short* __restrict__ Xvb,
    const unsigned short* __restrict__ Wqb, const unsigned short* __restrict__ Wkb,
    const unsigned short* __restrict__ Wvb,
    const float* __restrict__ bq, const float* __restrict__ bk, const float* __restrict__ bv,
    unsigned short* __restrict__ qh, unsigned short* __restrict__ kh,
    unsigned short* __restrict__ vh)
{
  const int p = blockIdx.z;
  const unsigned short* __restrict__ X = (p == 0) ? Xqb : (p == 1) ? Xkb : Xvb;
  const unsigned short* __restrict__ W = (p == 0) ? Wqb : (p == 1) ? Wkb : Wvb;
  const float* __restrict__ bias       = (p == 0) ? bq  : (p == 1) ? bk  : bv;
  unsigned short* __restrict__ dst     = (p == 0) ? qh  : (p == 1) ? kh  : vh;

  __shared__ unsigned short As[128][64];   // W rows (m = o)
  __shared__ unsigned short Bs[128][64];   // X rows (n = token)

  const int tid  = threadIdx.x;
  const int lane = tid & 63;
  const int w    = tid >> 6;
  const int wm   = (w & 1) * 64;
  const int wn   = (w >> 1) * 64;
  const int l15  = lane & 15;
  const int quad = lane >> 4;

  const int o0  = blockIdx.x * 128;
  const int t0b = blockIdx.y * 128;

  f32x4 acc[4][4];
#pragma unroll
  for (int mi = 0; mi < 4; ++mi)
#pragma unroll
    for (int ni = 0; ni < 4; ++ni) acc[mi][ni] = {0.f, 0.f, 0.f, 0.f};

  for (int kk = 0; kk < DEMB; kk += 64) {
#pragma unroll
    for (int r = 0; r < 4; ++r) {
      int idx = tid + r * 256;
      int row = idx >> 3, c = (idx & 7) * 8;
      gll16(&W[(size_t)(o0 + row) * DEMB + kk + c], (unsigned short*)As + idx * 8);
      gll16(&X[(size_t)(t0b + row) * DEMB + kk + c], (unsigned short*)Bs + idx * 8);
    }
    __syncthreads();
#pragma unroll
    for (int k0 = 0; k0 < 64; k0 += 32) {
      FragU af[4], bfr[4];
#pragma unroll
      for (int mi = 0; mi < 4; ++mi)
        af[mi].u = *(const uint4*)&As[wm + mi * 16 + l15][k0 + quad * 8];
#pragma unroll
      for (int ni = 0; ni < 4; ++ni)
        bfr[ni].u = *(const uint4*)&Bs[wn + ni * 16 + l15][k0 + quad * 8];
#pragma unroll
      for (int mi = 0; mi < 4; ++mi)
#pragma unroll
        for (int ni = 0; ni < 4; ++ni)
          acc[mi][ni] = __builtin_amdgcn_mfma_f32_16x16x32_bf16(af[mi].b, bfr[ni].b, acc[mi][ni], 0, 0, 0);
    }
    __syncthreads();
  }

#pragma unroll
  for (int mi = 0; mi < 4; ++mi) {
    const int ob = o0 + wm + mi * 16 + quad * 4;
    const float4 bi = *(const float4*)&bias[ob];
    const int h_ = ob >> 6, db = ob & 63;
#pragma unroll
    for (int ni = 0; ni < 4; ++ni) {
      int token = t0b + wn + ni * 16 + l15;
      int b_ = token >> 11, s_ = token & 2047;
      ushort4 ov;
      ov.x = f2bf(acc[mi][ni][0] + bi.x);
      ov.y = f2bf(acc[mi][ni][1] + bi.y);
      ov.z = f2bf(acc[mi][ni][2] + bi.z);
      ov.w = f2bf(acc[mi][ni][3] + bi.w);
      *(ushort4*)&dst[(((size_t)b_ * NHEAD + h_) * SEQ + s_) * DK + db] = ov;
    }
  }
}

// ---------------------------------------------------------------------------
// k_vt: coalesced LDS transpose vh [bh][s][d] -> vt [bh][d][s]
// ---------------------------------------------------------------------------
__global__ __launch_bounds__(256) void k_vt(const unsigned short* __restrict__ vh,
                                            unsigned short* __restrict__ vt)
{
  const int bh = blockIdx.y, s0 = blockIdx.x * 64;
  const size_t hoff = (size_t)bh * SEQ * DK;
  __shared__ unsigned short Ls[64][72];
  const int tid = threadIdx.x;
#pragma unroll
  for (int r = 0; r < 2; ++r) {
    int idx = tid + r * 256, row = idx >> 3, c = (idx & 7) * 8;
    uint4 v = *(const uint4*)&vh[hoff + (size_t)(s0 + row) * DK + c];
    *(uint4*)&Ls[row][c] = v;
  }
  __syncthreads();
#pragma unroll
  for (int r = 0; r < 2; ++r) {
    int idx = tid + r * 256, d = idx >> 3, c = (idx & 7) * 8;
    unsigned short tmp[8];
#pragma unroll
    for (int j = 0; j < 8; ++j) tmp[j] = Ls[c + j][d];
    *(uint4*)&vt[hoff + (size_t)d * SEQ + s0 + c] = *(const uint4*)tmp;
  }
}

// ---------------------------------------------------------------------------
// k_attn, round 3:
//  * XCD swizzle: 1024 blocks, XCD r gets heads [4r,4r+4) -> per-XCD K/V
//    working set 3MB fits the 4MB private L2 (was: all 32 heads = 24MB,
//    thrashed by the 537MB Pout store stream -> ~790MB HBM re-fetch).
//  * PV moved to pass 1 with UNNORMALIZED P (PV*rcp == (P*rcp)V): pass 2 is
//    now a pure streaming store pass (no LDS, 1 counted barrier/iter).
//  * s_setprio(1) around the PV MFMA cluster (T5).
// ---------------------------------------------------------------------------
__global__ __launch_bounds__(256, 3) void k_attn(
    const unsigned short* __restrict__ qh, const unsigned short* __restrict__ kh,
    const unsigned short* __restrict__ vt, unsigned short* __restrict__ blended,
    float* __restrict__ Pout)
{
  // bijective XCD swizzle (nwg=1024, nwg%8==0)
  const int linear  = blockIdx.y * 32 + blockIdx.x;
  const int logical = (linear & 7) * 128 + (linear >> 3);
  const int bh = logical >> 5;
  const int s0 = (logical & 31) * 64;
  const size_t hoff = (size_t)bh * SEQ * DK;

  __shared__ unsigned short Ks[2][64][64];   // 16KB, double-buffered
  __shared__ unsigned short Vs[2][64][64];   // 16KB, double-buffered ([d][t])
  __shared__ unsigned short Ps[64][64];      // 8KB, single buffer, swizzled
  float* rowpart = (float*)&Ps[0][0];        // scratch aliased onto Ps (post-loop)
  float* recipS  = rowpart + 256;

  const int tid  = threadIdx.x;
  const int lane = tid & 63;
  const int w    = tid >> 6;
  const int l15  = lane & 15;
  const int quad = lane >> 4;
  const int rx   = l15 & 7;

  // staging chunk mapping: LDS[r][j] holds global chunk (j ^ (r&7)) of row r
  const int p0 = tid, p1 = tid + 256;
  const int r0 = p0 >> 3, c0 = ((p0 & 7) ^ (r0 & 7)) * 8;
  const int r1 = p1 >> 3, c1 = ((p1 & 7) ^ (r1 & 7)) * 8;

  // Q fragments direct from global: once per block, L2-resident.
  FragU qf[4][2];
#pragma unroll
  for (int mi = 0; mi < 4; ++mi)
#pragma unroll
    for (int k0 = 0; k0 < 2; ++k0)
      qf[mi][k0].u = *(const uint4*)&qh[hoff + (size_t)(s0 + mi * 16 + l15) * DK + k0 * 32 + quad * 8];

  const int rr  = w * 16 + l15;         // K/V LDS row this lane's fragment uses
  const int fc0 = (quad ^ rx) * 8;      // swizzled frag chunk offsets (elems)
  const int fc1 = ((quad + 4) ^ rx) * 8;

  const int u   = w * 4 + quad;   // 8B unit within a P row
  const int psw = (((u >> 1) ^ rx) << 3) | ((u & 1) << 2);   // P write offs (elems)
  const int pr0 = (quad ^ rx) << 3;                          // P read offs
  const int pr1 = ((quad + 4) ^ rx) << 3;

  // ---- PASS 1: row sums + PV with unnormalized P. 2 barriers/iter. ----
  float rs[4] = {0.f, 0.f, 0.f, 0.f};
  f32x4 accpv[4];
#pragma unroll
  for (int mi = 0; mi < 4; ++mi) accpv[mi] = {0.f, 0.f, 0.f, 0.f};

  // prologue: stage tile 0
  gll16(&kh[hoff + (size_t)r0 * DK + c0], (unsigned short*)Ks[0] + p0 * 8);
  gll16(&kh[hoff + (size_t)r1 * DK + c1], (unsigned short*)Ks[0] + p1 * 8);
  gll16(&vt[hoff + (size_t)r0 * SEQ + c0], (unsigned short*)Vs[0] + p0 * 8);
  gll16(&vt[hoff + (size_t)r1 * SEQ + c1], (unsigned short*)Vs[0] + p1 * 8);
  BAR_VM0();

  for (int i = 0; i < 32; ++i) {
    const int b = i & 1;
    const size_t tn = (size_t)(((i + 1) & 31) * 64);   // wraparound prefetch
    gll16(&kh[hoff + (tn + r0) * DK + c0], (unsigned short*)Ks[b ^ 1] + p0 * 8);
    gll16(&kh[hoff + (tn + r1) * DK + c1], (unsigned short*)Ks[b ^ 1] + p1 * 8);
    gll16(&vt[hoff + (size_t)r0 * SEQ + tn + c0], (unsigned short*)Vs[b ^ 1] + p0 * 8);
    gll16(&vt[hoff + (size_t)r1 * SEQ + tn + c1], (unsigned short*)Vs[b ^ 1] + p1 * 8);
    FragU kf0, kf1, vf0, vf1;
    kf0.u = *(const uint4*)&Ks[b][rr][fc0];
    kf1.u = *(const uint4*)&Ks[b][rr][fc1];
    vf0.u = *(const uint4*)&Vs[b][rr][fc0];   // V frags pre-barrier -> PV reg-only + Ps
    vf1.u = *(const uint4*)&Vs[b][rr][fc1];
#pragma unroll
    for (int mi = 0; mi < 4; ++mi) {
      f32x4 a = {0.f, 0.f, 0.f, 0.f};
      a = __builtin_amdgcn_mfma_f32_16x16x32_bf16(kf0.b, qf[mi][0].b, a, 0, 0, 0);
      a = __builtin_amdgcn_mfma_f32_16x16x32_bf16(kf1.b, qf[mi][1].b, a, 0, 0, 0);
      float e0 = __expf(a[0] * 0.125f);
      float e1 = __expf(a[1] * 0.125f);
      float e2 = __expf(a[2] * 0.125f);
      float e3 = __expf(a[3] * 0.125f);
      rs[mi] += e0 + e1 + e2 + e3;
      ushort4 pb; pb.x = f2bf(e0); pb.y = f2bf(e1); pb.z = f2bf(e2); pb.w = f2bf(e3);
      *(ushort4*)((unsigned short*)&Ps[mi * 16 + l15][0] + psw) = pb;
    }
    BAR_LGKM();   // publish Ps; staging loads stay in flight
    __builtin_amdgcn_s_setprio(1);
#pragma unroll
    for (int mi = 0; mi < 4; ++mi) {
      FragU pf0, pf1;
      pf0.u = *(const uint4*)((const unsigned short*)&Ps[mi * 16 + l15][0] + pr0);
      pf1.u = *(const uint4*)((const unsigned short*)&Ps[mi * 16 + l15][0] + pr1);
      accpv[mi] = __builtin_amdgcn_mfma_f32_16x16x32_bf16(vf0.b, pf0.b, accpv[mi], 0, 0, 0);
      accpv[mi] = __builtin_amdgcn_mfma_f32_16x16x32_bf16(vf1.b, pf1.b, accpv[mi], 0, 0, 0);
    }
    __builtin_amdgcn_s_setprio(0);
    BAR_VM0();    // retire staging (issued a full iteration ago)
  }

  // reduce rs across quads (same s in lanes l15, l15+16, l15+32, l15+48)
#pragma unroll
  for (int mi = 0; mi < 4; ++mi) {
    float v = rs[mi];
    v += __shfl_xor(v, 16); v += __shfl_xor(v, 32);
    rs[mi] = v;
  }
  if (lane < 16) {
#pragma unroll
    for (int mi = 0; mi < 4; ++mi) rowpart[w * 64 + mi * 16 + lane] = rs[mi];
  }
  __syncthreads();
  if (tid < 64)
    recipS[tid] = 1.0f / (rowpart[tid] + rowpart[64 + tid] + rowpart[128 + tid] + rowpart[192 + tid]);
  __syncthreads();
  float rcp[4];
#pragma unroll
  for (int mi = 0; mi < 4; ++mi) rcp[mi] = recipS[mi * 16 + l15];

  // blended now: accpv (unnormalized) * rcp[s].  rows d = w*16+quad*4+i, s = mi*16+l15
  const int b_ = bh >> 4, h_ = bh & 15;
#pragma unroll
  for (int mi = 0; mi < 4; ++mi) {
    ushort4 ob;
    ob.x = f2bf(accpv[mi][0] * rcp[mi]); ob.y = f2bf(accpv[mi][1] * rcp[mi]);
    ob.z = f2bf(accpv[mi][2] * rcp[mi]); ob.w = f2bf(accpv[mi][3] * rcp[mi]);
    int token = b_ * SEQ + s0 + mi * 16 + l15;
    *(ushort4*)&blended[(size_t)token * DEMB + h_ * DK + w * 16 + quad * 4] = ob;
  }

  // ---- PASS 2: streaming Pout writes. No LDS use, 1 counted barrier/iter. ----
  gll16(&kh[hoff + (size_t)r0 * DK + c0], (unsigned short*)Ks[0] + p0 * 8);
  gll16(&kh[hoff + (size_t)r1 * DK + c1], (unsigned short*)Ks[0] + p1 * 8);
  BAR_VM0();

  for (int i = 0; i < 32; ++i) {
    const int b  = i & 1;
    const int t0 = i * 64;
    const size_t tn = (size_t)(((i + 1) & 31) * 64);
    gll16(&kh[hoff + (tn + r0) * DK + c0], (unsigned short*)Ks[b ^ 1] + p0 * 8);
    gll16(&kh[hoff + (tn + r1) * DK + c1], (unsigned short*)Ks[b ^ 1] + p1 * 8);
    FragU kf0, kf1;
    kf0.u = *(const uint4*)&Ks[b][rr][fc0];
    kf1.u = *(const uint4*)&Ks[b][rr][fc1];
#pragma unroll
    for (int mi = 0; mi < 4; ++mi) {
      f32x4 a = {0.f, 0.f, 0.f, 0.f};
      a = __builtin_amdgcn_mfma_f32_16x16x32_bf16(kf0.b, qf[mi][0].b, a, 0, 0, 0);
      a = __builtin_amdgcn_mfma_f32_16x16x32_bf16(kf1.b, qf[mi][1].b, a, 0, 0, 0);
      float4 p4;
      p4.x = __expf(a[0] * 0.125f) * rcp[mi];
      p4.y = __expf(a[1] * 0.125f) * rcp[mi];
      p4.z = __expf(a[2] * 0.125f) * rcp[mi];
      p4.w = __expf(a[3] * 0.125f) * rcp[mi];
      *(float4*)&Pout[((size_t)bh * SEQ + s0 + mi * 16 + l15) * SEQ + t0 + w * 16 + quad * 4] = p4;
    }
    // wave VMEM order this iter: 2 staging then 4 stores -> vmcnt(4) retires
    // exactly the staging; stores stay in flight.
    BAR_VM4();
  }
}

// ---------------------------------------------------------------------------
// k_outproj: D[m=o][n=token] = sum_k Wo[o][k] * blended[token][k] + bo[o]
// ---------------------------------------------------------------------------
__global__ __launch_bounds__(256) void k_outproj(
    const unsigned short* __restrict__ Wob, const unsigned short* __restrict__ blended,
    const float* __restrict__ bo, float* __restrict__ out)
{
  __shared__ unsigned short As[128][64];   // Wo rows (m = o)
  __shared__ unsigned short Bs[128][64];   // blended rows (n = token)

  const int tid  = threadIdx.x;
  const int lane = tid & 63;
  const int w    = tid >> 6;
  const int wm   = (w & 1) * 64;
  const int wn   = (w >> 1) * 64;
  const int l15  = lane & 15;
  const int quad = lane >> 4;

  const int o0  = blockIdx.x * 128;
  const int t0b = blockIdx.y * 128;

  f32x4 acc[4][4];
#pragma unroll
  for (int mi = 0; mi < 4; ++mi)
#pragma unroll
    for (int ni = 0; ni < 4; ++ni) acc[mi][ni] = {0.f, 0.f, 0.f, 0.f};

  for (int kk = 0; kk < DEMB; kk += 64) {
#pragma unroll
    for (int r = 0; r < 4; ++r) {
      int idx = tid + r * 256;
      int row = idx >> 3, c = (idx & 7) * 8;
      gll16(&Wob[(size_t)(o0 + row) * DEMB + kk + c], (unsigned short*)As + idx * 8);
      gll16(&blended[(size_t)(t0b + row) * DEMB + kk + c], (unsigned short*)Bs + idx * 8);
    }
    __syncthreads();
#pragma unroll
    for (int k0 = 0; k0 < 64; k0 += 32) {
      FragU af[4], bfr[4];
#pragma unroll
      for (int mi = 0; mi < 4; ++mi)
        af[mi].u = *(const uint4*)&As[wm + mi * 16 + l15][k0 + quad * 8];
#pragma unroll
      for (int ni = 0; ni < 4; ++ni)
        bfr[ni].u = *(const uint4*)&Bs[wn + ni * 16 + l15][k0 + quad * 8];
#pragma unroll
      for (int mi = 0; mi < 4; ++mi)
#pragma unroll
        for (int ni = 0; ni < 4; ++ni)
          acc[mi][ni] = __builtin_amdgcn_mfma_f32_16x16x32_bf16(af[mi].b, bfr[ni].b, acc[mi][ni], 0, 0, 0);
    }
    __syncthreads();
  }

#pragma unroll
  for (int mi = 0; mi < 4; ++mi) {
    const int ob = o0 + wm + mi * 16 + quad * 4;
    const float4 bi = *(const float4*)&bo[ob];
#pragma unroll
    for (int ni = 0; ni < 4; ++ni) {
      int token = t0b + wn + ni * 16 + l15;
      float4 ov;
      ov.x = acc[mi][ni][0] + bi.x;
      ov.y = acc[mi][ni][1] + bi.y;
      ov.z = acc[mi][ni][2] + bi.z;
      ov.w = acc[mi][ni][3] + bi.w;
      *(float4*)&out[(size_t)token * DEMB + ob] = ov;
    }
  }
}

// ---------------------------------------------------------------------------
extern "C" void kernel_launch(void* const* d_in, const int* in_sizes, int n_in,
                              void* d_out, int out_size, void* d_ws, size_t ws_size,
                              hipStream_t stream) {
  const float* Xq = (const float*)d_in[0];
  const float* Xk = (const float*)d_in[1];
  const float* Xv = (const float*)d_in[2];
  const float* Wq = (const float*)d_in[3];
  const float* bq = (const float*)d_in[4];
  const float* Wk = (const float*)d_in[5];
  const float* bk = (const float*)d_in[6];
  const float* Wv = (const float*)d_in[7];
  const float* bv = (const float*)d_in[8];
  const float* Wo = (const float*)d_in[9];
  const float* bo = (const float*)d_in[10];

  float* out  = (float*)d_out;
  float* Pout = out + OUT_ELEMS;

  // ws layout (bf16): 3 activations, 4 weights, qh/kh/vh/vt/blended
  unsigned short* Xqb = (unsigned short*)d_ws;
  unsigned short* Xkb = Xqb + OUT_ELEMS;
  unsigned short* Xvb = Xkb + OUT_ELEMS;
  unsigned short* Wqb = Xvb + OUT_ELEMS;
  unsigned short* Wkb = Wqb + (size_t)DEMB * DEMB;
  unsigned short* Wvb = Wkb + (size_t)DEMB * DEMB;
  unsigned short* Wob = Wvb + (size_t)DEMB * DEMB;
  unsigned short* qh      = Wob + (size_t)DEMB * DEMB;
  unsigned short* kh      = qh + OUT_ELEMS;
  unsigned short* vh      = kh + OUT_ELEMS;
  unsigned short* vt      = vh + OUT_ELEMS;
  unsigned short* blended = vt + OUT_ELEMS;

  k_cvt<<<dim3(1024, 7), 256, 0, stream>>>(Xq, Xk, Xv, Wq, Wk, Wv, Wo,
                                           Xqb, Xkb, Xvb, Wqb, Wkb, Wvb, Wob);
  k_proj<<<dim3(8, 32, 3), 256, 0, stream>>>(Xqb, Xkb, Xvb, Wqb, Wkb, Wvb,
                                             bq, bk, bv, qh, kh, vh);
  k_vt<<<dim3(32, 32), 256, 0, stream>>>(vh, vt);
  k_attn<<<dim3(SEQ / 64, BATCH * NHEAD), 256, 0, stream>>>(qh, kh, vt, blended, Pout);
  k_outproj<<<dim3(8, 32), 256, 0, stream>>>(Wob, blended, bo, out);
}